// Round 1
// baseline (295.130 us; speedup 1.0000x reference)
//
#include <hip/hip_runtime.h>
#include <math.h>

#define BQ 2
#define SQ 192
#define HQ 768
#define LQ 4

// Branchless exact-GELU: gelu(x) = x * Phi(x), Phi via erfc (A&S 7.1.26, |err|<=1.5e-7)
__device__ __forceinline__ float gelu_f(float x) {
  float z = fabsf(x) * 0.70710678118654752f;
  float t = __builtin_amdgcn_rcpf(fmaf(0.3275911f, z, 1.0f));
  float p = t * fmaf(t, fmaf(t, fmaf(t, fmaf(t, 1.061405429f, -1.453152027f),
                                     1.421413741f), -0.284496736f), 0.254829592f);
  float e = __builtin_amdgcn_exp2f(-z * z * 1.4426950408889634f);
  float erfc_z = p * e;                       // erfc(|x|/sqrt(2))
  float cdf = (x >= 0.f) ? fmaf(-0.5f, erfc_z, 1.0f) : (0.5f * erfc_z);
  return x * cdf;
}

// ---------------- Kernel 1: projections ----------------
// out[((b*L + l)*S + s)*H + h] = sum_k pooled[b*S+s][k] * W[l*H+h][k] + bias[l*H+h]
// M=384 (m=b*S+s), N=3072 (n=l*H+h), K=768. BM=BN=64, BK=32, 128 threads, 4m x 8n per thread.
__global__ __launch_bounds__(128) void proj_kernel(
    const float* __restrict__ A,
    const float* __restrict__ W0, const float* __restrict__ b0,
    const float* __restrict__ W1, const float* __restrict__ b1,
    float* __restrict__ o0, float* __restrict__ o1)
{
  const float* W  = blockIdx.z ? W1 : W0;
  const float* bs = blockIdx.z ? b1 : b0;
  float* out      = blockIdx.z ? o1 : o0;

  __shared__ float As[64][36];   // [m][k], columns XOR-swizzled by ((m>>2)&7)<<2
  __shared__ float Wt[32][68];   // [k][n] transposed

  const int tid = threadIdx.x;   // 0..127
  const int tx  = tid & 7;       // n-group: n = n0 + 8*tx + nn
  const int ty  = tid >> 3;      // 0..15:   m = m0 + 4*ty + j
  const int m0  = blockIdx.x * 64;
  const int n0  = blockIdx.y * 64;

  float acc[4][8];
  #pragma unroll
  for (int j = 0; j < 4; ++j)
    #pragma unroll
    for (int nn = 0; nn < 8; ++nn) acc[j][nn] = 0.f;

  for (int kt = 0; kt < HQ; kt += 32) {
    __syncthreads();
    // stage A tile 64x32 (coalesced float4, swizzled column)
    #pragma unroll
    for (int i = 0; i < 4; ++i) {
      int f4 = tid + i * 128;               // 0..511
      int r  = f4 >> 3;
      int c  = (f4 & 7) << 2;
      float4 v = *(const float4*)&A[(size_t)(m0 + r) * HQ + kt + c];
      int cs = c ^ (((r >> 2) & 7) << 2);
      *(float4*)&As[r][cs] = v;
    }
    // stage W tile transposed (coalesced float4 load, scalar scatter)
    #pragma unroll
    for (int i = 0; i < 4; ++i) {
      int f4 = tid + i * 128;
      int nr = f4 >> 3;
      int kc = (f4 & 7) << 2;
      float4 v = *(const float4*)&W[(size_t)(n0 + nr) * HQ + kt + kc];
      Wt[kc + 0][nr] = v.x; Wt[kc + 1][nr] = v.y;
      Wt[kc + 2][nr] = v.z; Wt[kc + 3][nr] = v.w;
    }
    __syncthreads();

    const int sw = (ty & 7) << 2;
    #pragma unroll
    for (int kk = 0; kk < 32; kk += 4) {
      float4 a[4], w[4][2];
      #pragma unroll
      for (int j = 0; j < 4; ++j)
        a[j] = *(float4*)&As[4 * ty + j][kk ^ sw];
      #pragma unroll
      for (int i = 0; i < 4; ++i) {
        w[i][0] = *(float4*)&Wt[kk + i][8 * tx];
        w[i][1] = *(float4*)&Wt[kk + i][8 * tx + 4];
      }
      #pragma unroll
      for (int i = 0; i < 4; ++i) {
        #pragma unroll
        for (int j = 0; j < 4; ++j) {
          float av = ((const float*)&a[j])[i];
          acc[j][0] = fmaf(av, w[i][0].x, acc[j][0]);
          acc[j][1] = fmaf(av, w[i][0].y, acc[j][1]);
          acc[j][2] = fmaf(av, w[i][0].z, acc[j][2]);
          acc[j][3] = fmaf(av, w[i][0].w, acc[j][3]);
          acc[j][4] = fmaf(av, w[i][1].x, acc[j][4]);
          acc[j][5] = fmaf(av, w[i][1].y, acc[j][5]);
          acc[j][6] = fmaf(av, w[i][1].z, acc[j][6]);
          acc[j][7] = fmaf(av, w[i][1].w, acc[j][7]);
        }
      }
    }
  }

  // epilogue: add bias, store to [b][l][s][h] layout
  const int l  = n0 / HQ;        // 768 % 64 == 0 -> constant per block
  const int h0 = n0 % HQ;
  float4 bv0 = *(const float4*)&bs[n0 + 8 * tx];
  float4 bv1 = *(const float4*)&bs[n0 + 8 * tx + 4];
  #pragma unroll
  for (int j = 0; j < 4; ++j) {
    int m  = m0 + 4 * ty + j;
    int bb = m / SQ, s = m % SQ;
    float* op = out + (((size_t)(bb * LQ + l) * SQ + s) * HQ) + h0 + 8 * tx;
    float4 v0, v1;
    v0.x = acc[j][0] + bv0.x; v0.y = acc[j][1] + bv0.y;
    v0.z = acc[j][2] + bv0.z; v0.w = acc[j][3] + bv0.w;
    v1.x = acc[j][4] + bv1.x; v1.y = acc[j][5] + bv1.y;
    v1.z = acc[j][6] + bv1.z; v1.w = acc[j][7] + bv1.w;
    *(float4*)op       = v0;
    *(float4*)(op + 4) = v1;
  }
}

// ---------------- Kernel 2: pairwise gelu-reduce ----------------
// out[b,s,t,l] = sum_h gelu(hs[b,l,s,h] + ht[b,l,t,h]) * cls[h,l]
// Block: 256 threads, tile 32 s x 16 t for one (b,l); each thread 2 outputs.
__global__ __launch_bounds__(256) void pair_kernel(
    const float* __restrict__ hsrc, const float* __restrict__ htgt,
    const float* __restrict__ cw, float* __restrict__ out)
{
  const int bl = blockIdx.z;         // b*L + l
  const int bb = bl >> 2, l = bl & 3;
  const int s0 = blockIdx.x * 32;
  const int t0 = blockIdx.y * 16;
  const int tid = threadIdx.x;
  const int tt = tid & 15;
  const int ts = tid >> 4;           // 0..15

  __shared__ float hs[32][260];      // pad 260 -> conflict-free column reads
  __shared__ float ht[16][260];
  __shared__ float cl[HQ];

  for (int i = tid; i < HQ; i += 256) cl[i] = cw[i * LQ + l];

  const float* hs_g = hsrc + ((size_t)bl * SQ + s0) * HQ;
  const float* ht_g = htgt + ((size_t)bl * SQ + t0) * HQ;

  float acc0 = 0.f, acc1 = 0.f;
  for (int ck = 0; ck < 3; ++ck) {
    __syncthreads();
    #pragma unroll
    for (int i = 0; i < 8; ++i) {     // hs: 32x256 = 2048 float4
      int f4 = tid + i * 256;
      int r  = f4 >> 6;
      int c  = (f4 & 63) << 2;
      *(float4*)&hs[r][c] = *(const float4*)&hs_g[(size_t)r * HQ + ck * 256 + c];
    }
    #pragma unroll
    for (int i = 0; i < 4; ++i) {     // ht: 16x256 = 1024 float4
      int f4 = tid + i * 256;
      int r  = f4 >> 6;
      int c  = (f4 & 63) << 2;
      *(float4*)&ht[r][c] = *(const float4*)&ht_g[(size_t)r * HQ + ck * 256 + c];
    }
    __syncthreads();

    #pragma unroll 4
    for (int k = 0; k < 256; k += 4) {
      float4 a0 = *(float4*)&hs[ts][k];
      float4 a1 = *(float4*)&hs[ts + 16][k];
      float4 b  = *(float4*)&ht[tt][k];
      float4 c4 = *(float4*)&cl[ck * 256 + k];
      acc0 = fmaf(gelu_f(a0.x + b.x), c4.x, acc0);
      acc0 = fmaf(gelu_f(a0.y + b.y), c4.y, acc0);
      acc0 = fmaf(gelu_f(a0.z + b.z), c4.z, acc0);
      acc0 = fmaf(gelu_f(a0.w + b.w), c4.w, acc0);
      acc1 = fmaf(gelu_f(a1.x + b.x), c4.x, acc1);
      acc1 = fmaf(gelu_f(a1.y + b.y), c4.y, acc1);
      acc1 = fmaf(gelu_f(a1.z + b.z), c4.z, acc1);
      acc1 = fmaf(gelu_f(a1.w + b.w), c4.w, acc1);
    }
  }

  size_t o0 = (((size_t)bb * SQ + (s0 + ts)) * SQ + (t0 + tt)) * LQ + l;
  size_t o1 = (((size_t)bb * SQ + (s0 + ts + 16)) * SQ + (t0 + tt)) * LQ + l;
  out[o0] = acc0;
  out[o1] = acc1;
}

extern "C" void kernel_launch(void* const* d_in, const int* in_sizes, int n_in,
                              void* d_out, int out_size, void* d_ws, size_t ws_size,
                              hipStream_t stream) {
  const float* pooled = (const float*)d_in[0];
  const float* Wsrc   = (const float*)d_in[1];
  const float* bsrc   = (const float*)d_in[2];
  const float* Wtgt   = (const float*)d_in[3];
  const float* btgt   = (const float*)d_in[4];
  const float* cw     = (const float*)d_in[5];
  float* out = (float*)d_out;

  float* hs = (float*)d_ws;                          // [B][L][S][H]
  float* ht = hs + (size_t)BQ * LQ * SQ * HQ;        // [B][L][S][H]

  proj_kernel<<<dim3(6, 48, 2), 128, 0, stream>>>(pooled, Wsrc, bsrc, Wtgt, btgt, hs, ht);
  pair_kernel<<<dim3(6, 12, 8), 256, 0, stream>>>(hs, ht, cw, out);
}

// Round 3
// 239.623 us; speedup vs baseline: 1.2316x; 1.2316x over previous
//
#include <hip/hip_runtime.h>
#include <math.h>

#define BQ 2
#define SQ 192
#define HQ 768
#define LQ 4

// Exact-GELU via A&S 7.1.25 erfc (3-term, |erf err|<=2.5e-5 -> gelu abs err <~1e-4).
// P = 0.5*erfc(|x|/sqrt2)  (0.5 folded into poly coeffs); select-free combine:
// gelu(x) = fma(-|x|, P, fma(0.5,|x|, 0.5x))   [x>=0: x(1-P); x<0: x*P]
__device__ __forceinline__ float gelu_f(float x) {
  float ax = fabsf(x);
  float z  = ax * 0.70710678118654752f;
  float t  = __builtin_amdgcn_rcpf(fmaf(0.47047f, z, 1.0f));
  float q  = t * fmaf(t, fmaf(t, 0.3739278f, -0.0479399f), 0.1740121f);
  float e  = __builtin_amdgcn_exp2f(z * z * -1.4426950408889634f);
  float P  = q * e;
  return fmaf(-ax, P, fmaf(0.5f, ax, 0.5f * x));
}

// ---------------- Kernel 1: projections ----------------
// out[((b*L+l)*S+s)*H+h] = sum_k pooled[m][k]*W[n][k] + bias[n],  m=b*S+s, n=l*H+h
// M=384, N=3072, K=768. BM=32, BN=64, BK=32; 256 threads; 2m x 4n per thread.
__global__ __launch_bounds__(256) void proj_kernel(
    const float* __restrict__ A,
    const float* __restrict__ W0, const float* __restrict__ b0,
    const float* __restrict__ W1, const float* __restrict__ b1,
    float* __restrict__ o0, float* __restrict__ o1)
{
  const float* W  = blockIdx.z ? W1 : W0;
  const float* bs = blockIdx.z ? b1 : b0;
  float* out      = blockIdx.z ? o1 : o0;

  __shared__ float As[32][36];   // [m][k], col xor-swizzled by ((m>>2)&7)<<2
  __shared__ float Wt[32][68];   // [k][n] transposed

  const int tid = threadIdx.x;
  const int tx  = tid & 15;      // n: 4 each
  const int ty  = tid >> 4;      // m: 2 each (0..15)
  const int m0  = blockIdx.x * 32;
  const int n0  = blockIdx.y * 64;

  float acc[2][4];
  #pragma unroll
  for (int j = 0; j < 2; ++j)
    #pragma unroll
    for (int n = 0; n < 4; ++n) acc[j][n] = 0.f;

  for (int kt = 0; kt < HQ; kt += 32) {
    __syncthreads();
    { // A tile 32x32 = 256 float4, 1 per thread
      int r  = tid >> 3;
      int c  = (tid & 7) << 2;
      float4 v = *(const float4*)&A[(size_t)(m0 + r) * HQ + kt + c];
      int cs = c ^ (((r >> 2) & 7) << 2);
      *(float4*)&As[r][cs] = v;
    }
    #pragma unroll
    for (int i = 0; i < 2; ++i) { // W tile 64x32 = 512 float4, transposed scatter
      int f4 = tid + i * 256;
      int nr = f4 >> 3;
      int kc = (f4 & 7) << 2;
      float4 v = *(const float4*)&W[(size_t)(n0 + nr) * HQ + kt + kc];
      Wt[kc + 0][nr] = v.x; Wt[kc + 1][nr] = v.y;
      Wt[kc + 2][nr] = v.z; Wt[kc + 3][nr] = v.w;
    }
    __syncthreads();

    #pragma unroll
    for (int kk = 0; kk < 32; kk += 4) {
      float4 a[2], w[4];
      #pragma unroll
      for (int j = 0; j < 2; ++j) {
        int r = 2 * ty + j;
        a[j] = *(float4*)&As[r][kk ^ (((r >> 2) & 7) << 2)];
      }
      #pragma unroll
      for (int i = 0; i < 4; ++i)
        w[i] = *(float4*)&Wt[kk + i][4 * tx];
      #pragma unroll
      for (int i = 0; i < 4; ++i) {
        #pragma unroll
        for (int j = 0; j < 2; ++j) {
          float av = ((const float*)&a[j])[i];
          acc[j][0] = fmaf(av, w[i].x, acc[j][0]);
          acc[j][1] = fmaf(av, w[i].y, acc[j][1]);
          acc[j][2] = fmaf(av, w[i].z, acc[j][2]);
          acc[j][3] = fmaf(av, w[i].w, acc[j][3]);
        }
      }
    }
  }

  const int l  = n0 / HQ;
  const int h0 = n0 % HQ;
  float4 bv = *(const float4*)&bs[n0 + 4 * tx];
  #pragma unroll
  for (int j = 0; j < 2; ++j) {
    int m  = m0 + 2 * ty + j;
    int bb = m / SQ, s = m % SQ;
    float4 v;
    v.x = acc[j][0] + bv.x; v.y = acc[j][1] + bv.y;
    v.z = acc[j][2] + bv.z; v.w = acc[j][3] + bv.w;
    *(float4*)(out + (((size_t)(bb * LQ + l) * SQ + s) * HQ) + h0 + 4 * tx) = v;
  }
}

// ---------------- Kernel 2: pairwise gelu-reduce ----------------
// out[b,s,t,l] = sum_h gelu(hs[b,l,s,h] + ht[b,l,t,h]) * cls[h,l]
// 16s x 16t tile per block, 256 threads, 1 output each.
__global__ __launch_bounds__(256) void pair_kernel(
    const float* __restrict__ hsrc, const float* __restrict__ htgt,
    const float* __restrict__ cw, float* __restrict__ out)
{
  const int bl = blockIdx.z;
  const int bb = bl >> 2, l = bl & 3;
  const int s0 = blockIdx.x * 16;
  const int t0 = blockIdx.y * 16;
  const int tid = threadIdx.x;
  const int tt = tid & 15;
  const int ts = tid >> 4;

  __shared__ float hs[16][260];
  __shared__ float ht[16][260];
  __shared__ float cl[HQ];

  for (int i = tid; i < HQ; i += 256) cl[i] = cw[i * LQ + l];

  const float* hs_g = hsrc + ((size_t)bl * SQ + s0) * HQ;
  const float* ht_g = htgt + ((size_t)bl * SQ + t0) * HQ;

  float acc0 = 0.f, acc1 = 0.f;
  for (int ck = 0; ck < 3; ++ck) {
    __syncthreads();
    #pragma unroll
    for (int i = 0; i < 4; ++i) {     // hs: 16x256 = 1024 float4
      int f4 = tid + i * 256;
      int r  = f4 >> 6;
      int c  = (f4 & 63) << 2;
      *(float4*)&hs[r][c] = *(const float4*)&hs_g[(size_t)r * HQ + ck * 256 + c];
    }
    #pragma unroll
    for (int i = 0; i < 4; ++i) {     // ht: 16x256 = 1024 float4
      int f4 = tid + i * 256;
      int r  = f4 >> 6;
      int c  = (f4 & 63) << 2;
      *(float4*)&ht[r][c] = *(const float4*)&ht_g[(size_t)r * HQ + ck * 256 + c];
    }
    __syncthreads();

    #pragma unroll 4
    for (int k = 0; k < 256; k += 4) {
      float4 a  = *(float4*)&hs[ts][k];
      float4 b  = *(float4*)&ht[tt][k];
      float4 c4 = *(float4*)&cl[ck * 256 + k];
      acc0 = fmaf(gelu_f(a.x + b.x), c4.x, acc0);
      acc1 = fmaf(gelu_f(a.y + b.y), c4.y, acc1);
      acc0 = fmaf(gelu_f(a.z + b.z), c4.z, acc0);
      acc1 = fmaf(gelu_f(a.w + b.w), c4.w, acc1);
    }
  }

  size_t o = (((size_t)bb * SQ + (s0 + ts)) * SQ + (t0 + tt)) * LQ + l;
  out[o] = acc0 + acc1;
}

extern "C" void kernel_launch(void* const* d_in, const int* in_sizes, int n_in,
                              void* d_out, int out_size, void* d_ws, size_t ws_size,
                              hipStream_t stream) {
  const float* pooled = (const float*)d_in[0];
  const float* Wsrc   = (const float*)d_in[1];
  const float* bsrc   = (const float*)d_in[2];
  const float* Wtgt   = (const float*)d_in[3];
  const float* btgt   = (const float*)d_in[4];
  const float* cw     = (const float*)d_in[5];
  float* out = (float*)d_out;

  float* hs = (float*)d_ws;                          // [B][L][S][H]
  float* ht = hs + (size_t)BQ * LQ * SQ * HQ;        // [B][L][S][H]

  proj_kernel<<<dim3(12, 48, 2), 256, 0, stream>>>(pooled, Wsrc, bsrc, Wtgt, btgt, hs, ht);
  pair_kernel<<<dim3(12, 12, 8), 256, 0, stream>>>(hs, ht, cw, out);
}

// Round 5
// 237.675 us; speedup vs baseline: 1.2417x; 1.0082x over previous
//
#include <hip/hip_runtime.h>
#include <math.h>

#define BQ 2
#define SQ 192
#define HQ 768
#define LQ 4

// Exact-GELU via A&S 7.1.27: erf(z) ~ 1 - 1/(1+a1 z+a2 z^2+a3 z^3+a4 z^4)^4, |err|<=5e-4.
// Constants pre-scaled: z=|x|/sqrt2 folded in (b_i = a_i/2^{i/2}) and 2^{1/4} folded in
// (c_i = b_i * 2^{1/4}) so r4 = 1/q'^4 = 0.5*(1-erf(|x|/sqrt2)) = Phi(-|x|) directly.
// gelu(x) = max(x,0) - |x|*Phi(-|x|).  10 VALU + 1 rcp, no exp.
__device__ __forceinline__ float gelu_f(float x) {
  float ax = fabsf(x);
  float q = fmaf(fmaf(fmaf(fmaf(0.0232217f, ax, 0.00040867f), ax, 0.1369901f),
                      ax, 0.2340973f), ax, 1.18920712f);
  float r  = __builtin_amdgcn_rcpf(q);
  float r2 = r * r;
  float r4 = r2 * r2;                 // Phi(-|x|)
  return fmaf(-ax, r4, fmaxf(x, 0.f));
}

// ---------------- Kernel 0: pack classifier weights ----------------
// clp[l*H + h] = cw[h*L + l]  (3072 elems) -> enables wave-uniform scalar loads in pair.
__global__ __launch_bounds__(256) void pack_kernel(const float* __restrict__ cw,
                                                   float* __restrict__ clp) {
  int i = blockIdx.x * 256 + threadIdx.x;   // 0..3071
  int l = i / HQ, h = i % HQ;
  clp[i] = cw[h * LQ + l];
}

// ---------------- Kernel 1: projections ----------------
// out[((b*L+l)*S+s)*H+h] = sum_k pooled[m][k]*W[n][k] + bias[n],  m=b*S+s, n=l*H+h
// M=384, N=3072, K=768. BM=32, BN=64, BK=64; 256 threads; 2m x 4n per thread.
// Register-prefetch of next K-tile issued right after ds_writes -> L3 latency hides
// under the 16-quad compute phase. 24 barriers total (BK=64).
__global__ __launch_bounds__(256) void proj_kernel(
    const float* __restrict__ A,
    const float* __restrict__ W0, const float* __restrict__ b0,
    const float* __restrict__ W1, const float* __restrict__ b1,
    float* __restrict__ o0, float* __restrict__ o1)
{
  const float* W  = blockIdx.z ? W1 : W0;
  const float* bs = blockIdx.z ? b1 : b0;
  float* out      = blockIdx.z ? o1 : o0;

  __shared__ float As[32][68];   // [m][k]  (stride 68: 2-way bank alias = free)
  __shared__ float Wt[64][68];   // [k][n] transposed

  const int tid = threadIdx.x;
  const int tx  = tid & 15;      // n-group: n = n0 + 4*tx + nn
  const int ty  = tid >> 4;      // m-group: m = m0 + 2*ty + j
  const int m0  = blockIdx.x * 32;
  const int n0  = blockIdx.y * 64;

  // staging coords (A: 32x64 = 512 f4, 2/thread; W: 64x64 = 1024 f4, 4/thread)
  const int ar[2] = { (tid + 0)   >> 4, (tid + 256) >> 4 };
  const int ac    = (tid & 15) << 2;
  const int wr[4] = { tid >> 4, (tid + 256) >> 4, (tid + 512) >> 4, (tid + 768) >> 4 };
  const int wc    = (tid & 15) << 2;

  float4 pa[2], pw[4];
  #pragma unroll
  for (int i = 0; i < 2; ++i)
    pa[i] = *(const float4*)&A[(size_t)(m0 + ar[i]) * HQ + ac];
  #pragma unroll
  for (int i = 0; i < 4; ++i)
    pw[i] = *(const float4*)&W[(size_t)(n0 + wr[i]) * HQ + wc];

  float acc[2][4];
  #pragma unroll
  for (int j = 0; j < 2; ++j)
    #pragma unroll
    for (int n = 0; n < 4; ++n) acc[j][n] = 0.f;

  for (int kt = 0; kt < 12; ++kt) {
    __syncthreads();               // previous compute done; LDS reusable
    #pragma unroll
    for (int i = 0; i < 2; ++i)
      *(float4*)&As[ar[i]][ac] = pa[i];
    #pragma unroll
    for (int i = 0; i < 4; ++i) {
      Wt[wc + 0][wr[i]] = pw[i].x; Wt[wc + 1][wr[i]] = pw[i].y;
      Wt[wc + 2][wr[i]] = pw[i].z; Wt[wc + 3][wr[i]] = pw[i].w;
    }
    if (kt < 11) {                 // issue next-tile loads; consumed after next barrier
      int ko = (kt + 1) * 64;
      #pragma unroll
      for (int i = 0; i < 2; ++i)
        pa[i] = *(const float4*)&A[(size_t)(m0 + ar[i]) * HQ + ko + ac];
      #pragma unroll
      for (int i = 0; i < 4; ++i)
        pw[i] = *(const float4*)&W[(size_t)(n0 + wr[i]) * HQ + ko + wc];
    }
    __syncthreads();               // LDS tile ready

    #pragma unroll
    for (int kk = 0; kk < 64; kk += 4) {
      float4 a[2], w[4];
      #pragma unroll
      for (int j = 0; j < 2; ++j)
        a[j] = *(float4*)&As[2 * ty + j][kk];
      #pragma unroll
      for (int i = 0; i < 4; ++i)
        w[i] = *(float4*)&Wt[kk + i][4 * tx];
      #pragma unroll
      for (int i = 0; i < 4; ++i) {
        #pragma unroll
        for (int j = 0; j < 2; ++j) {
          float av = ((const float*)&a[j])[i];
          acc[j][0] = fmaf(av, w[i].x, acc[j][0]);
          acc[j][1] = fmaf(av, w[i].y, acc[j][1]);
          acc[j][2] = fmaf(av, w[i].z, acc[j][2]);
          acc[j][3] = fmaf(av, w[i].w, acc[j][3]);
        }
      }
    }
  }

  const int l  = n0 / HQ;          // 768 % 64 == 0 -> uniform per block
  const int h0 = n0 % HQ;
  float4 bv = *(const float4*)&bs[n0 + 4 * tx];
  #pragma unroll
  for (int j = 0; j < 2; ++j) {
    int m  = m0 + 2 * ty + j;
    int bb = m / SQ, s = m % SQ;
    float4 v;
    v.x = acc[j][0] + bv.x; v.y = acc[j][1] + bv.y;
    v.z = acc[j][2] + bv.z; v.w = acc[j][3] + bv.w;
    *(float4*)(out + (((size_t)(bb * LQ + l) * SQ + s) * HQ) + h0 + 4 * tx) = v;
  }
}

// ---------------- Kernel 2: pairwise gelu-reduce ----------------
// out[b,s,t,l] = sum_h gelu(hs[b,l,s,h] + ht[b,l,t,h]) * clp[l,h]
// 16s x 16t per block, 256 threads, 1 output each; clp via wave-uniform (scalar) loads.
__global__ __launch_bounds__(256) void pair_kernel(
    const float* __restrict__ hsrc, const float* __restrict__ htgt,
    const float* __restrict__ clp, float* __restrict__ out)
{
  const int bl = blockIdx.z;
  const int bb = bl >> 2, l = bl & 3;
  const int s0 = blockIdx.x * 16;
  const int t0 = blockIdx.y * 16;
  const int tid = threadIdx.x;
  const int tt = tid & 15;
  const int ts = tid >> 4;

  __shared__ float hs[16][260];
  __shared__ float ht[16][260];

  const float* hs_g  = hsrc + ((size_t)bl * SQ + s0) * HQ;
  const float* ht_g  = htgt + ((size_t)bl * SQ + t0) * HQ;
  const float* clp_l = clp + l * HQ;        // uniform across block

  float acc = 0.f;
  for (int ck = 0; ck < 3; ++ck) {
    __syncthreads();
    #pragma unroll
    for (int i = 0; i < 4; ++i) {     // hs: 16x256 = 1024 float4
      int f4 = tid + i * 256;
      int r  = f4 >> 6;
      int c  = (f4 & 63) << 2;
      *(float4*)&hs[r][c] = *(const float4*)&hs_g[(size_t)r * HQ + ck * 256 + c];
    }
    #pragma unroll
    for (int i = 0; i < 4; ++i) {     // ht: 16x256 = 1024 float4
      int f4 = tid + i * 256;
      int r  = f4 >> 6;
      int c  = (f4 & 63) << 2;
      *(float4*)&ht[r][c] = *(const float4*)&ht_g[(size_t)r * HQ + ck * 256 + c];
    }
    __syncthreads();

    #pragma unroll 4
    for (int k = 0; k < 256; k += 4) {
      float4 a  = *(float4*)&hs[ts][k];
      float4 b  = *(float4*)&ht[tt][k];
      float4 c4 = *(const float4*)&clp_l[ck * 256 + k];   // uniform -> s_load
      acc = fmaf(gelu_f(a.x + b.x), c4.x, acc);
      acc = fmaf(gelu_f(a.y + b.y), c4.y, acc);
      acc = fmaf(gelu_f(a.z + b.z), c4.z, acc);
      acc = fmaf(gelu_f(a.w + b.w), c4.w, acc);
    }
  }

  out[(((size_t)bb * SQ + (s0 + ts)) * SQ + (t0 + tt)) * LQ + l] = acc;
}

extern "C" void kernel_launch(void* const* d_in, const int* in_sizes, int n_in,
                              void* d_out, int out_size, void* d_ws, size_t ws_size,
                              hipStream_t stream) {
  const float* pooled = (const float*)d_in[0];
  const float* Wsrc   = (const float*)d_in[1];
  const float* bsrc   = (const float*)d_in[2];
  const float* Wtgt   = (const float*)d_in[3];
  const float* btgt   = (const float*)d_in[4];
  const float* cw     = (const float*)d_in[5];
  float* out = (float*)d_out;

  float* hs  = (float*)d_ws;                          // [B][L][S][H]
  float* ht  = hs + (size_t)BQ * LQ * SQ * HQ;        // [B][L][S][H]
  float* clp = ht + (size_t)BQ * LQ * SQ * HQ;        // [L][H]

  pack_kernel<<<dim3(12), 256, 0, stream>>>(cw, clp);
  proj_kernel<<<dim3(12, 48, 2), 256, 0, stream>>>(pooled, Wsrc, bsrc, Wtgt, btgt, hs, ht);
  pair_kernel<<<dim3(12, 12, 8), 256, 0, stream>>>(hs, ht, clp, out);
}

// Round 7
// 177.841 us; speedup vs baseline: 1.6595x; 1.3365x over previous
//
#include <hip/hip_runtime.h>
#include <math.h>

#define BQ 2
#define SQ 192
#define HQ 768
#define LQ 4

typedef float f2    __attribute__((ext_vector_type(2)));
typedef float f32x4 __attribute__((ext_vector_type(4)));
typedef short bf16x8 __attribute__((ext_vector_type(8)));

// Packed exact-GELU (A&S 7.1.27, |erf err|<=5e-4), two elements per op via v_pk_*.
// r4 = 1/q^4 = Phi(-|x|);  gelu = max(x,0) - |x|*Phi(-|x|).
__device__ __forceinline__ f2 gelu2(f2 x) {
  f2 ax = __builtin_elementwise_abs(x);
  f2 q  = __builtin_elementwise_fma((f2)0.0232217f, ax, (f2)0.00040867f);
  q     = __builtin_elementwise_fma(q, ax, (f2)0.1369901f);
  q     = __builtin_elementwise_fma(q, ax, (f2)0.2340973f);
  q     = __builtin_elementwise_fma(q, ax, (f2)1.18920712f);
  f2 r;
  r.x = __builtin_amdgcn_rcpf(q.x);
  r.y = __builtin_amdgcn_rcpf(q.y);
  f2 r2 = r * r;
  f2 r4 = r2 * r2;
  f2 relu = __builtin_elementwise_max(x, (f2)0.0f);
  return __builtin_elementwise_fma(-ax, r4, relu);
}

__device__ __forceinline__ unsigned short bf16_rne(float x) {
  unsigned u = __float_as_uint(x);
  return (unsigned short)((u + 0x7fffu + ((u >> 16) & 1u)) >> 16);
}

// ---------------- Kernel 0: prep — bf16 conversion + classifier pack ----------------
// Ab = bf16(pooled); Wsb/Wtb = bf16(W); clp[l*H+h] = cw[h*L+l]
__global__ __launch_bounds__(256) void prep_kernel(
    const float* __restrict__ pooled, const float* __restrict__ Ws,
    const float* __restrict__ Wt, const float* __restrict__ cw,
    unsigned short* __restrict__ Ab, unsigned short* __restrict__ Wsb,
    unsigned short* __restrict__ Wtb, float* __restrict__ clp)
{
  const int NAq = (BQ * SQ * HQ) / 4;           // 73728 quads
  const int NWq = (LQ * HQ * HQ) / 4;           // 589824 quads
  const int total = NAq + 2 * NWq;
  int gid = blockIdx.x * 256 + threadIdx.x;
  if (gid < LQ * HQ) {                          // 3072: pack classifier
    int l = gid / HQ, h = gid % HQ;
    clp[gid] = cw[h * LQ + l];
  }
  for (int i = gid; i < total; i += gridDim.x * 256) {
    const float* src; unsigned short* dst; int j;
    if (i < NAq)            { src = pooled; dst = Ab;  j = i; }
    else if (i < NAq + NWq) { src = Ws;     dst = Wsb; j = i - NAq; }
    else                    { src = Wt;     dst = Wtb; j = i - NAq - NWq; }
    float4 v = *(const float4*)&src[(size_t)j * 4];
    ushort4 o;
    o.x = bf16_rne(v.x); o.y = bf16_rne(v.y);
    o.z = bf16_rne(v.z); o.w = bf16_rne(v.w);
    *(ushort4*)&dst[(size_t)j * 4] = o;
  }
}

// ---------------- Kernel 1a: projections via bf16 MFMA (no LDS) ----------------
// out[((bb*L+l)*S+s)*H+h] = sum_k A[m][k]*W[n][k] + bias[n];  m=bb*S+s, n=l*H+h
// M=384, N=3072, K=768. Block 64x64 (4 waves, 32x32 each), K-step 32.
// A/B frag: row(col)=lane&15, k=(lane>>4)*8+j — consistent bijection on both operands.
// C/D: col=lane&15, row=(lane>>4)*4+reg  [m89-verified].
__global__ __launch_bounds__(256) void proj_mfma(
    const unsigned short* __restrict__ Ab,
    const unsigned short* __restrict__ Wsb, const unsigned short* __restrict__ Wtb,
    const float* __restrict__ b0, const float* __restrict__ b1,
    float* __restrict__ o0, float* __restrict__ o1)
{
  // XCD-chunked bijective swizzle (576 = 8*72)
  int id  = blockIdx.x + 6 * (blockIdx.y + 48 * blockIdx.z);
  int nid = (id & 7) * 72 + (id >> 3);
  int bx = nid % 6, by = (nid / 6) % 48, bz = nid / 288;

  const unsigned short* W = bz ? Wtb : Wsb;
  const float* bias = bz ? b1 : b0;
  float* out        = bz ? o1 : o0;

  int tid  = threadIdx.x;
  int w    = tid >> 6;
  int lane = tid & 63;
  int wm = w >> 1, wn = w & 1;
  int m_base = bx * 64 + wm * 32;
  int n_base = by * 64 + wn * 32;
  int r = lane & 15, g = lane >> 4;

  const unsigned short* a0p = Ab + (size_t)(m_base + r) * HQ + g * 8;
  const unsigned short* a1p = a0p + 16 * HQ;
  const unsigned short* w0p = W + (size_t)(n_base + r) * HQ + g * 8;
  const unsigned short* w1p = w0p + 16 * HQ;

  f32x4 acc00 = {0,0,0,0}, acc01 = {0,0,0,0}, acc10 = {0,0,0,0}, acc11 = {0,0,0,0};

  bf16x8 a0 = *(const bf16x8*)a0p, a1 = *(const bf16x8*)a1p;
  bf16x8 v0 = *(const bf16x8*)w0p, v1 = *(const bf16x8*)w1p;
  for (int kt = 0; kt < 23; ++kt) {
    int off = (kt + 1) * 32;
    bf16x8 na0 = *(const bf16x8*)(a0p + off), na1 = *(const bf16x8*)(a1p + off);
    bf16x8 nv0 = *(const bf16x8*)(w0p + off), nv1 = *(const bf16x8*)(w1p + off);
    acc00 = __builtin_amdgcn_mfma_f32_16x16x32_bf16(a0, v0, acc00, 0, 0, 0);
    acc01 = __builtin_amdgcn_mfma_f32_16x16x32_bf16(a0, v1, acc01, 0, 0, 0);
    acc10 = __builtin_amdgcn_mfma_f32_16x16x32_bf16(a1, v0, acc10, 0, 0, 0);
    acc11 = __builtin_amdgcn_mfma_f32_16x16x32_bf16(a1, v1, acc11, 0, 0, 0);
    a0 = na0; a1 = na1; v0 = nv0; v1 = nv1;
  }
  acc00 = __builtin_amdgcn_mfma_f32_16x16x32_bf16(a0, v0, acc00, 0, 0, 0);
  acc01 = __builtin_amdgcn_mfma_f32_16x16x32_bf16(a0, v1, acc01, 0, 0, 0);
  acc10 = __builtin_amdgcn_mfma_f32_16x16x32_bf16(a1, v0, acc10, 0, 0, 0);
  acc11 = __builtin_amdgcn_mfma_f32_16x16x32_bf16(a1, v1, acc11, 0, 0, 0);

  // epilogue
  int l      = n_base / HQ;        // uniform per block (32 | 768)
  int h_base = n_base % HQ;
  int bb     = m_base / SQ;        // uniform per block (32 | 192)
  int c      = lane & 15;
  float bv0 = bias[n_base + c];
  float bv1 = bias[n_base + 16 + c];
  #pragma unroll
  for (int i = 0; i < 2; ++i) {
    f32x4 A0 = i ? acc10 : acc00;
    f32x4 A1 = i ? acc11 : acc01;
    #pragma unroll
    for (int reg = 0; reg < 4; ++reg) {
      int m = m_base + i * 16 + g * 4 + reg;
      int s = m - bb * SQ;
      float* op = out + (((size_t)(bb * LQ + l) * SQ + s) * HQ) + h_base;
      op[c]      = A0[reg] + bv0;
      op[16 + c] = A1[reg] + bv1;
    }
  }
}

// ---------------- Kernel 1b: f32 fallback projection (if ws too small) ----------------
__global__ __launch_bounds__(256) void proj_kernel(
    const float* __restrict__ A,
    const float* __restrict__ W0, const float* __restrict__ b0,
    const float* __restrict__ W1, const float* __restrict__ b1,
    float* __restrict__ o0, float* __restrict__ o1)
{
  const float* W  = blockIdx.z ? W1 : W0;
  const float* bs = blockIdx.z ? b1 : b0;
  float* out      = blockIdx.z ? o1 : o0;

  __shared__ float As[32][68];
  __shared__ float Wt[64][68];

  const int tid = threadIdx.x;
  const int tx  = tid & 15;
  const int ty  = tid >> 4;
  const int m0  = blockIdx.x * 32;
  const int n0  = blockIdx.y * 64;

  const int ar[2] = { (tid + 0) >> 4, (tid + 256) >> 4 };
  const int ac    = (tid & 15) << 2;
  const int wr[4] = { tid >> 4, (tid + 256) >> 4, (tid + 512) >> 4, (tid + 768) >> 4 };
  const int wc    = (tid & 15) << 2;

  float4 pa[2], pw[4];
  #pragma unroll
  for (int i = 0; i < 2; ++i)
    pa[i] = *(const float4*)&A[(size_t)(m0 + ar[i]) * HQ + ac];
  #pragma unroll
  for (int i = 0; i < 4; ++i)
    pw[i] = *(const float4*)&W[(size_t)(n0 + wr[i]) * HQ + wc];

  float acc[2][4];
  #pragma unroll
  for (int j = 0; j < 2; ++j)
    #pragma unroll
    for (int n = 0; n < 4; ++n) acc[j][n] = 0.f;

  for (int kt = 0; kt < 12; ++kt) {
    __syncthreads();
    #pragma unroll
    for (int i = 0; i < 2; ++i)
      *(float4*)&As[ar[i]][ac] = pa[i];
    #pragma unroll
    for (int i = 0; i < 4; ++i) {
      Wt[wc + 0][wr[i]] = pw[i].x; Wt[wc + 1][wr[i]] = pw[i].y;
      Wt[wc + 2][wr[i]] = pw[i].z; Wt[wc + 3][wr[i]] = pw[i].w;
    }
    if (kt < 11) {
      int ko = (kt + 1) * 64;
      #pragma unroll
      for (int i = 0; i < 2; ++i)
        pa[i] = *(const float4*)&A[(size_t)(m0 + ar[i]) * HQ + ko + ac];
      #pragma unroll
      for (int i = 0; i < 4; ++i)
        pw[i] = *(const float4*)&W[(size_t)(n0 + wr[i]) * HQ + ko + wc];
    }
    __syncthreads();

    #pragma unroll
    for (int kk = 0; kk < 64; kk += 4) {
      float4 a[2], wv[4];
      #pragma unroll
      for (int j = 0; j < 2; ++j)
        a[j] = *(float4*)&As[2 * ty + j][kk];
      #pragma unroll
      for (int i = 0; i < 4; ++i)
        wv[i] = *(float4*)&Wt[kk + i][4 * tx];
      #pragma unroll
      for (int i = 0; i < 4; ++i) {
        #pragma unroll
        for (int j = 0; j < 2; ++j) {
          float av = ((const float*)&a[j])[i];
          acc[j][0] = fmaf(av, wv[i].x, acc[j][0]);
          acc[j][1] = fmaf(av, wv[i].y, acc[j][1]);
          acc[j][2] = fmaf(av, wv[i].z, acc[j][2]);
          acc[j][3] = fmaf(av, wv[i].w, acc[j][3]);
        }
      }
    }
  }

  const int l  = n0 / HQ;
  const int h0 = n0 % HQ;
  float4 bv = *(const float4*)&bs[n0 + 4 * tx];
  #pragma unroll
  for (int j = 0; j < 2; ++j) {
    int m  = m0 + 2 * ty + j;
    int bb = m / SQ, s = m % SQ;
    float4 v;
    v.x = acc[j][0] + bv.x; v.y = acc[j][1] + bv.y;
    v.z = acc[j][2] + bv.z; v.w = acc[j][3] + bv.w;
    *(float4*)(out + (((size_t)(bb * LQ + l) * SQ + s) * HQ) + h0 + 4 * tx) = v;
  }
}

__global__ __launch_bounds__(256) void pack_kernel(const float* __restrict__ cw,
                                                   float* __restrict__ clp) {
  int i = blockIdx.x * 256 + threadIdx.x;
  int l = i / HQ, h = i % HQ;
  clp[i] = cw[h * LQ + l];
}

// ---------------- Kernel 2: pairwise gelu-reduce (packed f32x2) ----------------
// out[b,s,t,l] = sum_h gelu(hs[b,l,s,h] + ht[b,l,t,h]) * clp[l,h]
__global__ __launch_bounds__(256) void pair_kernel(
    const float* __restrict__ hsrc, const float* __restrict__ htgt,
    const float* __restrict__ clp, float* __restrict__ out)
{
  // XCD-chunked bijective swizzle (1152 = 8*144): each XCD gets one (b,l) slab.
  int id  = blockIdx.x + 12 * (blockIdx.y + 12 * blockIdx.z);
  int nid = (id & 7) * 144 + (id >> 3);
  int bix = nid % 12, biy = (nid / 12) % 12, bl = nid / 144;

  const int bb = bl >> 2, l = bl & 3;
  const int s0 = bix * 16;
  const int t0 = biy * 16;
  const int tid = threadIdx.x;
  const int tt = tid & 15;
  const int ts = tid >> 4;

  __shared__ float hs[16][260];
  __shared__ float ht[16][260];

  const float* hs_g  = hsrc + ((size_t)bl * SQ + s0) * HQ;
  const float* ht_g  = htgt + ((size_t)bl * SQ + t0) * HQ;
  const float* clp_l = clp + l * HQ;

  f2 acc = {0.f, 0.f};
  for (int ck = 0; ck < 3; ++ck) {
    __syncthreads();
    #pragma unroll
    for (int i = 0; i < 4; ++i) {
      int f4 = tid + i * 256;
      int r  = f4 >> 6;
      int c  = (f4 & 63) << 2;
      *(float4*)&hs[r][c] = *(const float4*)&hs_g[(size_t)r * HQ + ck * 256 + c];
    }
    #pragma unroll
    for (int i = 0; i < 4; ++i) {
      int f4 = tid + i * 256;
      int r  = f4 >> 6;
      int c  = (f4 & 63) << 2;
      *(float4*)&ht[r][c] = *(const float4*)&ht_g[(size_t)r * HQ + ck * 256 + c];
    }
    __syncthreads();

    #pragma unroll 4
    for (int k = 0; k < 256; k += 4) {
      float4 a  = *(float4*)&hs[ts][k];
      float4 b  = *(float4*)&ht[tt][k];
      float4 c4 = *(const float4*)&clp_l[ck * 256 + k];
      const f2* ap = (const f2*)&a;
      const f2* bp = (const f2*)&b;
      const f2* cp = (const f2*)&c4;
      acc = __builtin_elementwise_fma(gelu2(ap[0] + bp[0]), cp[0], acc);
      acc = __builtin_elementwise_fma(gelu2(ap[1] + bp[1]), cp[1], acc);
    }
  }

  out[(((size_t)bb * SQ + (s0 + ts)) * SQ + (t0 + tt)) * LQ + l] = acc.x + acc.y;
}

extern "C" void kernel_launch(void* const* d_in, const int* in_sizes, int n_in,
                              void* d_out, int out_size, void* d_ws, size_t ws_size,
                              hipStream_t stream) {
  const float* pooled = (const float*)d_in[0];
  const float* Wsrc   = (const float*)d_in[1];
  const float* bsrc   = (const float*)d_in[2];
  const float* Wtgt   = (const float*)d_in[3];
  const float* btgt   = (const float*)d_in[4];
  const float* cw     = (const float*)d_in[5];
  float* out = (float*)d_out;

  const size_t nhs = (size_t)BQ * LQ * SQ * HQ;     // 1,179,648
  float* clp = (float*)d_ws;                        // [L][H]
  float* hs  = clp + LQ * HQ;                       // [B][L][S][H] f32
  float* ht  = hs + nhs;
  unsigned short* Ab  = (unsigned short*)(ht + nhs);          // 294,912 bf16
  unsigned short* Wsb = Ab + (size_t)BQ * SQ * HQ;            // 2,359,296 bf16
  unsigned short* Wtb = Wsb + (size_t)LQ * HQ * HQ;

  size_t need_full = (size_t)(LQ * HQ + 2 * nhs) * 4 +
                     (size_t)(BQ * SQ * HQ + 2 * LQ * HQ * HQ) * 2;

  if (ws_size >= need_full) {
    prep_kernel<<<dim3(1024), 256, 0, stream>>>(pooled, Wsrc, Wtgt, cw, Ab, Wsb, Wtb, clp);
    proj_mfma<<<dim3(6, 48, 2), 256, 0, stream>>>(Ab, Wsb, Wtb, bsrc, btgt, hs, ht);
  } else {
    pack_kernel<<<dim3(12), 256, 0, stream>>>(cw, clp);
    proj_kernel<<<dim3(12, 48, 2), 256, 0, stream>>>(pooled, Wsrc, bsrc, Wtgt, btgt, hs, ht);
  }
  pair_kernel<<<dim3(12, 12, 8), 256, 0, stream>>>(hs, ht, clp, out);
}

// Round 10
// 174.245 us; speedup vs baseline: 1.6938x; 1.0206x over previous
//
#include <hip/hip_runtime.h>
#include <math.h>

#define BQ 2
#define SQ 192
#define HQ 768
#define LQ 4

typedef float f32x4 __attribute__((ext_vector_type(4)));
typedef short bf16x8 __attribute__((ext_vector_type(8)));

// Exact-GELU via A&S 7.1.27 (no exp): r4 = (1 + c1 u + c2 u^2 + c3 u^3 + c4 u^4)^-4
// with constants pre-scaled so r4 = Phi(-|x|).  gelu = max(x,0) - |x|*Phi(-|x|).
__device__ __forceinline__ float gelu_f(float x) {
  float ax = fabsf(x);
  float q = fmaf(fmaf(fmaf(fmaf(0.0232217f, ax, 0.00040867f), ax, 0.1369901f),
                      ax, 0.2340973f), ax, 1.18920712f);
  float r  = __builtin_amdgcn_rcpf(q);
  float r2 = r * r;
  float r4 = r2 * r2;                 // Phi(-|x|)
  return fmaf(-ax, r4, fmaxf(x, 0.f));
}

__device__ __forceinline__ unsigned short bf16_rne(float x) {
  unsigned u = __float_as_uint(x);
  return (unsigned short)((u + 0x7fffu + ((u >> 16) & 1u)) >> 16);
}

// ---------------- Kernel 0: prep — bf16 fragment-pack + classifier pack ----------------
// Packed layout per matrix X[R][768]:
//   XP[((rt*24 + kt)*64 + lane)*8 + j] = bf16(X[rt*16 + (lane&15)][kt*32 + (lane>>4)*8 + j])
// so proj's fragment load is base + lane*16B (fully coalesced).
// Blocks 0..23: A(384 rows); 24..215: Ws(3072); 216..407: Wt(3072); 408..419: clp.
__global__ __launch_bounds__(256) void prep_kernel(
    const float* __restrict__ pooled, const float* __restrict__ Ws,
    const float* __restrict__ Wt, const float* __restrict__ cw,
    unsigned short* __restrict__ Ab, unsigned short* __restrict__ Wsb,
    unsigned short* __restrict__ Wtb, float* __restrict__ clp)
{
  int blk = blockIdx.x;
  if (blk >= 408) {                       // classifier pack: clp[l*768+h] = cw[h*4+l]
    int i = (blk - 408) * 256 + threadIdx.x;     // 0..3071
    clp[i] = cw[(i % HQ) * LQ + i / HQ];
    return;
  }
  const float* src; unsigned short* dst; int rt;
  if (blk < 24)       { src = pooled; dst = Ab;  rt = blk; }
  else if (blk < 216) { src = Ws;     dst = Wsb; rt = blk - 24; }
  else                { src = Wt;     dst = Wtb; rt = blk - 216; }

  #pragma unroll
  for (int i = 0; i < 6; ++i) {           // 1536 chunks / 256 threads
    int c    = threadIdx.x + i * 256;
    int kt   = c >> 6;
    int lane = c & 63;
    int row  = rt * 16 + (lane & 15);
    int col  = kt * 32 + (lane >> 4) * 8;
    const float* s = src + (size_t)row * HQ + col;
    float4 v0 = *(const float4*)s;
    float4 v1 = *(const float4*)(s + 4);
    ushort4 o0, o1;
    o0.x = bf16_rne(v0.x); o0.y = bf16_rne(v0.y);
    o0.z = bf16_rne(v0.z); o0.w = bf16_rne(v0.w);
    o1.x = bf16_rne(v1.x); o1.y = bf16_rne(v1.y);
    o1.z = bf16_rne(v1.z); o1.w = bf16_rne(v1.w);
    unsigned short* d = dst + ((size_t)(rt * 24 + kt) * 64 + lane) * 8;
    *(ushort4*)d       = o0;
    *(ushort4*)(d + 4) = o1;
  }
}

// ---------------- Kernel 1a: projections via bf16 MFMA, packed-coalesced frags ----------
// 1 wave per block; wave computes a 32x32 tile via 4 accumulators, K=768 in 24 steps.
// A/B frag: row=lane&15, k=kt*32+(lane>>4)*8+j (same bijection both operands — validated R7).
// C/D: col=lane&15, row=(lane>>4)*4+reg  [m89].
__global__ __launch_bounds__(64) void proj_mfma(
    const unsigned short* __restrict__ APk,
    const unsigned short* __restrict__ WsPk, const unsigned short* __restrict__ WtPk,
    const float* __restrict__ b0, const float* __restrict__ b1,
    float* __restrict__ o0, float* __restrict__ o1)
{
  // flatten 12 x 96 x 2 = 2304 blocks, XCD-chunk swizzle (2304 = 8*288)
  int id  = blockIdx.x + 12 * (blockIdx.y + 96 * blockIdx.z);
  int nid = (id & 7) * 288 + (id >> 3);
  int bm = nid % 12, bn = (nid / 12) % 96, bz = nid / 1152;

  const unsigned short* WPk = bz ? WtPk : WsPk;
  const float* bias = bz ? b1 : b0;
  float* out        = bz ? o1 : o0;

  int lane = threadIdx.x;
  int m_base = bm * 32, n_base = bn * 32;

  const unsigned short* a0p = APk + (size_t)(bm * 2) * 24 * 512 + lane * 8;
  const unsigned short* a1p = a0p + 24 * 512;
  const unsigned short* w0p = WPk + (size_t)(bn * 2) * 24 * 512 + lane * 8;
  const unsigned short* w1p = w0p + 24 * 512;

  f32x4 acc00 = {0,0,0,0}, acc01 = {0,0,0,0}, acc10 = {0,0,0,0}, acc11 = {0,0,0,0};

  bf16x8 a0 = *(const bf16x8*)a0p, a1 = *(const bf16x8*)a1p;
  bf16x8 v0 = *(const bf16x8*)w0p, v1 = *(const bf16x8*)w1p;
  for (int kt = 0; kt < 23; ++kt) {
    int off = (kt + 1) * 512;
    bf16x8 na0 = *(const bf16x8*)(a0p + off), na1 = *(const bf16x8*)(a1p + off);
    bf16x8 nv0 = *(const bf16x8*)(w0p + off), nv1 = *(const bf16x8*)(w1p + off);
    acc00 = __builtin_amdgcn_mfma_f32_16x16x32_bf16(a0, v0, acc00, 0, 0, 0);
    acc01 = __builtin_amdgcn_mfma_f32_16x16x32_bf16(a0, v1, acc01, 0, 0, 0);
    acc10 = __builtin_amdgcn_mfma_f32_16x16x32_bf16(a1, v0, acc10, 0, 0, 0);
    acc11 = __builtin_amdgcn_mfma_f32_16x16x32_bf16(a1, v1, acc11, 0, 0, 0);
    a0 = na0; a1 = na1; v0 = nv0; v1 = nv1;
  }
  acc00 = __builtin_amdgcn_mfma_f32_16x16x32_bf16(a0, v0, acc00, 0, 0, 0);
  acc01 = __builtin_amdgcn_mfma_f32_16x16x32_bf16(a0, v1, acc01, 0, 0, 0);
  acc10 = __builtin_amdgcn_mfma_f32_16x16x32_bf16(a1, v0, acc10, 0, 0, 0);
  acc11 = __builtin_amdgcn_mfma_f32_16x16x32_bf16(a1, v1, acc11, 0, 0, 0);

  int l      = n_base / HQ;        // uniform (32 | 768)
  int h_base = n_base % HQ;
  int bb     = m_base / SQ;        // uniform (32 | 192)
  int c      = lane & 15, g = lane >> 4;
  float bv0 = bias[n_base + c];
  float bv1 = bias[n_base + 16 + c];
  #pragma unroll
  for (int i = 0; i < 2; ++i) {
    f32x4 A0 = i ? acc10 : acc00;
    f32x4 A1 = i ? acc11 : acc01;
    #pragma unroll
    for (int reg = 0; reg < 4; ++reg) {
      int m = m_base + i * 16 + g * 4 + reg;
      int s = m - bb * SQ;
      float* op = out + (((size_t)(bb * LQ + l) * SQ + s) * HQ) + h_base;
      op[c]      = A0[reg] + bv0;
      op[16 + c] = A1[reg] + bv1;
    }
  }
}

// ---------------- Kernel 1b: f32 fallback projection (if ws too small) ----------------
__global__ __launch_bounds__(256) void proj_kernel(
    const float* __restrict__ A,
    const float* __restrict__ W0, const float* __restrict__ b0,
    const float* __restrict__ W1, const float* __restrict__ b1,
    float* __restrict__ o0, float* __restrict__ o1)
{
  const float* W  = blockIdx.z ? W1 : W0;
  const float* bs = blockIdx.z ? b1 : b0;
  float* out      = blockIdx.z ? o1 : o0;

  __shared__ float As[32][68];
  __shared__ float Wt[64][68];

  const int tid = threadIdx.x;
  const int tx  = tid & 15;
  const int ty  = tid >> 4;
  const int m0  = blockIdx.x * 32;
  const int n0  = blockIdx.y * 64;

  const int ar[2] = { (tid + 0) >> 4, (tid + 256) >> 4 };
  const int ac    = (tid & 15) << 2;
  const int wr[4] = { tid >> 4, (tid + 256) >> 4, (tid + 512) >> 4, (tid + 768) >> 4 };
  const int wc    = (tid & 15) << 2;

  float4 pa[2], pw[4];
  #pragma unroll
  for (int i = 0; i < 2; ++i)
    pa[i] = *(const float4*)&A[(size_t)(m0 + ar[i]) * HQ + ac];
  #pragma unroll
  for (int i = 0; i < 4; ++i)
    pw[i] = *(const float4*)&W[(size_t)(n0 + wr[i]) * HQ + wc];

  float acc[2][4];
  #pragma unroll
  for (int j = 0; j < 2; ++j)
    #pragma unroll
    for (int n = 0; n < 4; ++n) acc[j][n] = 0.f;

  for (int kt = 0; kt < 12; ++kt) {
    __syncthreads();
    #pragma unroll
    for (int i = 0; i < 2; ++i)
      *(float4*)&As[ar[i]][ac] = pa[i];
    #pragma unroll
    for (int i = 0; i < 4; ++i) {
      Wt[wc + 0][wr[i]] = pw[i].x; Wt[wc + 1][wr[i]] = pw[i].y;
      Wt[wc + 2][wr[i]] = pw[i].z; Wt[wc + 3][wr[i]] = pw[i].w;
    }
    if (kt < 11) {
      int ko = (kt + 1) * 64;
      #pragma unroll
      for (int i = 0; i < 2; ++i)
        pa[i] = *(const float4*)&A[(size_t)(m0 + ar[i]) * HQ + ko + ac];
      #pragma unroll
      for (int i = 0; i < 4; ++i)
        pw[i] = *(const float4*)&W[(size_t)(n0 + wr[i]) * HQ + ko + wc];
    }
    __syncthreads();

    #pragma unroll
    for (int kk = 0; kk < 64; kk += 4) {
      float4 a[2], wv[4];
      #pragma unroll
      for (int j = 0; j < 2; ++j)
        a[j] = *(float4*)&As[2 * ty + j][kk];
      #pragma unroll
      for (int i = 0; i < 4; ++i)
        wv[i] = *(float4*)&Wt[kk + i][4 * tx];
      #pragma unroll
      for (int i = 0; i < 4; ++i) {
        #pragma unroll
        for (int j = 0; j < 2; ++j) {
          float av = ((const float*)&a[j])[i];
          acc[j][0] = fmaf(av, wv[i].x, acc[j][0]);
          acc[j][1] = fmaf(av, wv[i].y, acc[j][1]);
          acc[j][2] = fmaf(av, wv[i].z, acc[j][2]);
          acc[j][3] = fmaf(av, wv[i].w, acc[j][3]);
        }
      }
    }
  }

  const int l  = n0 / HQ;
  const int h0 = n0 % HQ;
  float4 bv = *(const float4*)&bs[n0 + 4 * tx];
  #pragma unroll
  for (int j = 0; j < 2; ++j) {
    int m  = m0 + 2 * ty + j;
    int bb = m / SQ, s = m % SQ;
    float4 v;
    v.x = acc[j][0] + bv.x; v.y = acc[j][1] + bv.y;
    v.z = acc[j][2] + bv.z; v.w = acc[j][3] + bv.w;
    *(float4*)(out + (((size_t)(bb * LQ + l) * SQ + s) * HQ) + h0 + 4 * tx) = v;
  }
}

__global__ __launch_bounds__(256) void pack_kernel(const float* __restrict__ cw,
                                                   float* __restrict__ clp) {
  int i = blockIdx.x * 256 + threadIdx.x;
  int l = i / HQ, h = i % HQ;
  clp[i] = cw[h * LQ + l];
}

// ---------------- Kernel 2: pairwise gelu-reduce ----------------
// out[b,s,t,l] = sum_h gelu(hs[b,l,s,h] + ht[b,l,t,h]) * clp[l,h]
// 16s x 16t per block. Only ht staged in LDS (XOR-swizzled, 16 KB -> 8 blocks/CU);
// hs via 16-lane-uniform global reads; clp via wave-uniform s_load.
__global__ __launch_bounds__(256, 8) void pair_kernel(
    const float* __restrict__ hsrc, const float* __restrict__ htgt,
    const float* __restrict__ clp, float* __restrict__ out)
{
  // XCD-chunked bijective swizzle (1152 = 8*144): each XCD gets one (b,l) slab.
  int id  = blockIdx.x + 12 * (blockIdx.y + 12 * blockIdx.z);
  int nid = (id & 7) * 144 + (id >> 3);
  int bix = nid % 12, biy = (nid / 12) % 12, bl = nid / 144;

  const int bb = bl >> 2, l = bl & 3;
  const int s0 = bix * 16;
  const int t0 = biy * 16;
  const int tid = threadIdx.x;
  const int tt = tid & 15;
  const int ts = tid >> 4;

  __shared__ float htile[16][256];    // [t][h-chunk], col XOR-swizzled by ((t&7)<<2)

  const float* hs_row = hsrc + ((size_t)bl * SQ + s0 + ts) * HQ;
  const float* ht_g   = htgt + ((size_t)bl * SQ + t0) * HQ;
  const float* clp_l  = clp + l * HQ;           // uniform across block

  const int tsw = (tt & 7) << 2;

  float acc = 0.f;
  for (int ck = 0; ck < 3; ++ck) {
    __syncthreads();
    #pragma unroll
    for (int i = 0; i < 4; ++i) {     // ht chunk: 16 rows x 256 cols = 1024 float4
      int f4 = tid + i * 256;
      int r  = f4 >> 6;
      int cq = (f4 & 63) << 2;
      float4 v = *(const float4*)&ht_g[(size_t)r * HQ + ck * 256 + cq];
      *(float4*)&htile[r][cq ^ ((r & 7) << 2)] = v;
    }
    __syncthreads();

    #pragma unroll 4
    for (int k = 0; k < 256; k += 4) {
      float4 a  = *(const float4*)&hs_row[ck * 256 + k];      // 16-lane uniform
      float4 b  = *(float4*)&htile[tt][k ^ tsw];
      float4 c4 = *(const float4*)&clp_l[ck * 256 + k];       // s_load
      acc = fmaf(gelu_f(a.x + b.x), c4.x, acc);
      acc = fmaf(gelu_f(a.y + b.y), c4.y, acc);
      acc = fmaf(gelu_f(a.z + b.z), c4.z, acc);
      acc = fmaf(gelu_f(a.w + b.w), c4.w, acc);
    }
  }

  out[(((size_t)bb * SQ + (s0 + ts)) * SQ + (t0 + tt)) * LQ + l] = acc;
}

extern "C" void kernel_launch(void* const* d_in, const int* in_sizes, int n_in,
                              void* d_out, int out_size, void* d_ws, size_t ws_size,
                              hipStream_t stream) {
  const float* pooled = (const float*)d_in[0];
  const float* Wsrc   = (const float*)d_in[1];
  const float* bsrc   = (const float*)d_in[2];
  const float* Wtgt   = (const float*)d_in[3];
  const float* btgt   = (const float*)d_in[4];
  const float* cw     = (const float*)d_in[5];
  float* out = (float*)d_out;

  const size_t nhs = (size_t)BQ * LQ * SQ * HQ;     // 1,179,648
  float* clp = (float*)d_ws;                        // [L][H]
  float* hs  = clp + LQ * HQ;                       // [B][L][S][H] f32
  float* ht  = hs + nhs;
  unsigned short* Ab  = (unsigned short*)(ht + nhs);          // packed frags
  unsigned short* Wsb = Ab + (size_t)BQ * SQ * HQ;
  unsigned short* Wtb = Wsb + (size_t)LQ * HQ * HQ;

  size_t need_full = (size_t)(LQ * HQ + 2 * nhs) * 4 +
                     (size_t)(BQ * SQ * HQ + 2 * LQ * HQ * HQ) * 2;

  if (ws_size >= need_full) {
    prep_kernel<<<dim3(420), 256, 0, stream>>>(pooled, Wsrc, Wtgt, cw, Ab, Wsb, Wtb, clp);
    proj_mfma<<<dim3(12, 96, 2), 64, 0, stream>>>(Ab, Wsb, Wtb, bsrc, btgt, hs, ht);
  } else {
    pack_kernel<<<dim3(12), 256, 0, stream>>>(cw, clp);
    proj_kernel<<<dim3(12, 48, 2), 256, 0, stream>>>(pooled, Wsrc, bsrc, Wtgt, btgt, hs, ht);
  }
  pair_kernel<<<dim3(12, 12, 8), 256, 0, stream>>>(hs, ht, clp, out);
}

// Round 11
// 155.603 us; speedup vs baseline: 1.8967x; 1.1198x over previous
//
#include <hip/hip_runtime.h>
#include <math.h>

#define BQ 2
#define SQ 192
#define HQ 768
#define LQ 4

typedef float  f2     __attribute__((ext_vector_type(2)));
typedef float  f32x4  __attribute__((ext_vector_type(4)));
typedef short  bf16x8 __attribute__((ext_vector_type(8)));
typedef unsigned short u16x8 __attribute__((ext_vector_type(8)));

// Packed exact-GELU (A&S 7.1.27, |erf err|<=5e-4). r4 = Phi(-|x|);
// gelu = max(x,0) - |x|*Phi(-|x|).  [R5-measured best: 75.4us pair]
__device__ __forceinline__ f2 gelu2(f2 x) {
  f2 ax = __builtin_elementwise_abs(x);
  f2 q  = __builtin_elementwise_fma((f2)0.0232217f, ax, (f2)0.00040867f);
  q     = __builtin_elementwise_fma(q, ax, (f2)0.1369901f);
  q     = __builtin_elementwise_fma(q, ax, (f2)0.2340973f);
  q     = __builtin_elementwise_fma(q, ax, (f2)1.18920712f);
  f2 r;
  r.x = __builtin_amdgcn_rcpf(q.x);
  r.y = __builtin_amdgcn_rcpf(q.y);
  f2 r2 = r * r;
  f2 r4 = r2 * r2;
  f2 relu = __builtin_elementwise_max(x, (f2)0.0f);
  return __builtin_elementwise_fma(-ax, r4, relu);
}

__device__ __forceinline__ unsigned short bf16_rne(float x) {
  unsigned u = __float_as_uint(x);
  return (unsigned short)((u + 0x7fffu + ((u >> 16) & 1u)) >> 16);
}
__device__ __forceinline__ float b2f(unsigned short u) {
  return __uint_as_float((unsigned)u << 16);
}

// ---------------- Kernel 0: prep — bf16 fragment-pack + classifier pack ----------------
// XP[((rt*24+kt)*64+lane)*8+j] = bf16(X[rt*16+(lane&15)][kt*32+(lane>>4)*8+j])
// Blocks 0..2447: 408 rt-units x 6 sub-chunks. Blocks 2448..2459: clp pack.
__global__ __launch_bounds__(256) void prep_kernel(
    const float* __restrict__ pooled, const float* __restrict__ Ws,
    const float* __restrict__ Wt, const float* __restrict__ cw,
    unsigned short* __restrict__ Ab, unsigned short* __restrict__ Wsb,
    unsigned short* __restrict__ Wtb, float* __restrict__ clp)
{
  int blk = blockIdx.x;
  if (blk >= 2448) {                      // clp[l*768+h] = cw[h*4+l]
    int i = (blk - 2448) * 256 + threadIdx.x;
    clp[i] = cw[(i % HQ) * LQ + i / HQ];
    return;
  }
  int unit = blk / 6, sub = blk % 6;
  const float* src; unsigned short* dst; int rt;
  if (unit < 24)       { src = pooled; dst = Ab;  rt = unit; }
  else if (unit < 216) { src = Ws;     dst = Wsb; rt = unit - 24; }
  else                 { src = Wt;     dst = Wtb; rt = unit - 216; }

  int c    = threadIdx.x + sub * 256;     // 0..1535
  int kt   = c >> 6;
  int lane = c & 63;
  int row  = rt * 16 + (lane & 15);
  int col  = kt * 32 + (lane >> 4) * 8;
  const float* s = src + (size_t)row * HQ + col;
  float4 v0 = *(const float4*)s;
  float4 v1 = *(const float4*)(s + 4);
  ushort4 o0, o1;
  o0.x = bf16_rne(v0.x); o0.y = bf16_rne(v0.y);
  o0.z = bf16_rne(v0.z); o0.w = bf16_rne(v0.w);
  o1.x = bf16_rne(v1.x); o1.y = bf16_rne(v1.y);
  o1.z = bf16_rne(v1.z); o1.w = bf16_rne(v1.w);
  unsigned short* d = dst + ((size_t)(rt * 24 + kt) * 64 + lane) * 8;
  *(ushort4*)d       = o0;
  *(ushort4*)(d + 4) = o1;
}

// ---------------- Kernel 1a: projections via bf16 MFMA, depth-2 ping-pong --------------
// 1 wave/block; 32x32 tile, K=768 in 24 steps (2 per iteration, A/B reg sets).
// Frag bijection validated R7 (absmax 0.0156). C/D: col=lane&15, row=(lane>>4)*4+reg.
// Outputs hs/ht in BF16.
__global__ __launch_bounds__(64) void proj_mfma(
    const unsigned short* __restrict__ APk,
    const unsigned short* __restrict__ WsPk, const unsigned short* __restrict__ WtPk,
    const float* __restrict__ b0, const float* __restrict__ b1,
    unsigned short* __restrict__ o0, unsigned short* __restrict__ o1)
{
  int id  = blockIdx.x + 12 * (blockIdx.y + 96 * blockIdx.z);
  int nid = (id & 7) * 288 + (id >> 3);          // XCD chunk (2304 = 8*288)
  int bm = nid % 12, bn = (nid / 12) % 96, bz = nid / 1152;

  const unsigned short* WPk = bz ? WtPk : WsPk;
  const float* bias = bz ? b1 : b0;
  unsigned short* out = bz ? o1 : o0;

  int lane = threadIdx.x;
  int m_base = bm * 32, n_base = bn * 32;

  const unsigned short* a0p = APk + (size_t)(bm * 2) * 24 * 512 + lane * 8;
  const unsigned short* a1p = a0p + 24 * 512;
  const unsigned short* w0p = WPk + (size_t)(bn * 2) * 24 * 512 + lane * 8;
  const unsigned short* w1p = w0p + 24 * 512;

  f32x4 acc00 = {0,0,0,0}, acc01 = {0,0,0,0}, acc10 = {0,0,0,0}, acc11 = {0,0,0,0};

  // depth-2: A-set holds even kt, B-set holds odd kt
  bf16x8 A0 = *(const bf16x8*)a0p,        A1 = *(const bf16x8*)a1p;
  bf16x8 U0 = *(const bf16x8*)w0p,        U1 = *(const bf16x8*)w1p;
  bf16x8 B0 = *(const bf16x8*)(a0p+512),  B1 = *(const bf16x8*)(a1p+512);
  bf16x8 X0 = *(const bf16x8*)(w0p+512),  X1 = *(const bf16x8*)(w1p+512);

  #pragma unroll
  for (int it = 0; it < 11; ++it) {
    int offA = (2 * it + 2) * 512;
    int offB = (2 * it + 3) * 512;
    bf16x8 nA0 = *(const bf16x8*)(a0p + offA), nA1 = *(const bf16x8*)(a1p + offA);
    bf16x8 nU0 = *(const bf16x8*)(w0p + offA), nU1 = *(const bf16x8*)(w1p + offA);
    acc00 = __builtin_amdgcn_mfma_f32_16x16x32_bf16(A0, U0, acc00, 0, 0, 0);
    acc01 = __builtin_amdgcn_mfma_f32_16x16x32_bf16(A0, U1, acc01, 0, 0, 0);
    acc10 = __builtin_amdgcn_mfma_f32_16x16x32_bf16(A1, U0, acc10, 0, 0, 0);
    acc11 = __builtin_amdgcn_mfma_f32_16x16x32_bf16(A1, U1, acc11, 0, 0, 0);
    A0 = nA0; A1 = nA1; U0 = nU0; U1 = nU1;
    bf16x8 nB0 = *(const bf16x8*)(a0p + offB), nB1 = *(const bf16x8*)(a1p + offB);
    bf16x8 nX0 = *(const bf16x8*)(w0p + offB), nX1 = *(const bf16x8*)(w1p + offB);
    acc00 = __builtin_amdgcn_mfma_f32_16x16x32_bf16(B0, X0, acc00, 0, 0, 0);
    acc01 = __builtin_amdgcn_mfma_f32_16x16x32_bf16(B0, X1, acc01, 0, 0, 0);
    acc10 = __builtin_amdgcn_mfma_f32_16x16x32_bf16(B1, X0, acc10, 0, 0, 0);
    acc11 = __builtin_amdgcn_mfma_f32_16x16x32_bf16(B1, X1, acc11, 0, 0, 0);
    B0 = nB0; B1 = nB1; X0 = nX0; X1 = nX1;
  }
  acc00 = __builtin_amdgcn_mfma_f32_16x16x32_bf16(A0, U0, acc00, 0, 0, 0);
  acc01 = __builtin_amdgcn_mfma_f32_16x16x32_bf16(A0, U1, acc01, 0, 0, 0);
  acc10 = __builtin_amdgcn_mfma_f32_16x16x32_bf16(A1, U0, acc10, 0, 0, 0);
  acc11 = __builtin_amdgcn_mfma_f32_16x16x32_bf16(A1, U1, acc11, 0, 0, 0);
  acc00 = __builtin_amdgcn_mfma_f32_16x16x32_bf16(B0, X0, acc00, 0, 0, 0);
  acc01 = __builtin_amdgcn_mfma_f32_16x16x32_bf16(B0, X1, acc01, 0, 0, 0);
  acc10 = __builtin_amdgcn_mfma_f32_16x16x32_bf16(B1, X0, acc10, 0, 0, 0);
  acc11 = __builtin_amdgcn_mfma_f32_16x16x32_bf16(B1, X1, acc11, 0, 0, 0);

  int l      = n_base / HQ;        // uniform (32 | 768)
  int h_base = n_base % HQ;
  int bb     = m_base / SQ;        // uniform (32 | 192)
  int c      = lane & 15, g = lane >> 4;
  float bv0 = bias[n_base + c];
  float bv1 = bias[n_base + 16 + c];
  #pragma unroll
  for (int i = 0; i < 2; ++i) {
    f32x4 C0 = i ? acc10 : acc00;
    f32x4 C1 = i ? acc11 : acc01;
    #pragma unroll
    for (int reg = 0; reg < 4; ++reg) {
      int m = m_base + i * 16 + g * 4 + reg;
      int s = m - bb * SQ;
      unsigned short* op = out + (((size_t)(bb * LQ + l) * SQ + s) * HQ) + h_base;
      op[c]      = bf16_rne(C0[reg] + bv0);
      op[16 + c] = bf16_rne(C1[reg] + bv1);
    }
  }
}

// ---------------- Kernel 1b: f32-LDS fallback projection (writes bf16) -----------------
__global__ __launch_bounds__(256) void proj_kernel(
    const float* __restrict__ A,
    const float* __restrict__ W0, const float* __restrict__ b0,
    const float* __restrict__ W1, const float* __restrict__ b1,
    unsigned short* __restrict__ o0, unsigned short* __restrict__ o1)
{
  const float* W  = blockIdx.z ? W1 : W0;
  const float* bs = blockIdx.z ? b1 : b0;
  unsigned short* out = blockIdx.z ? o1 : o0;

  __shared__ float As[32][68];
  __shared__ float Wt[64][68];

  const int tid = threadIdx.x;
  const int tx  = tid & 15;
  const int ty  = tid >> 4;
  const int m0  = blockIdx.x * 32;
  const int n0  = blockIdx.y * 64;

  const int ar[2] = { (tid + 0) >> 4, (tid + 256) >> 4 };
  const int ac    = (tid & 15) << 2;
  const int wr[4] = { tid >> 4, (tid + 256) >> 4, (tid + 512) >> 4, (tid + 768) >> 4 };
  const int wc    = (tid & 15) << 2;

  float4 pa[2], pw[4];
  #pragma unroll
  for (int i = 0; i < 2; ++i)
    pa[i] = *(const float4*)&A[(size_t)(m0 + ar[i]) * HQ + ac];
  #pragma unroll
  for (int i = 0; i < 4; ++i)
    pw[i] = *(const float4*)&W[(size_t)(n0 + wr[i]) * HQ + wc];

  float acc[2][4];
  #pragma unroll
  for (int j = 0; j < 2; ++j)
    #pragma unroll
    for (int n = 0; n < 4; ++n) acc[j][n] = 0.f;

  for (int kt = 0; kt < 12; ++kt) {
    __syncthreads();
    #pragma unroll
    for (int i = 0; i < 2; ++i)
      *(float4*)&As[ar[i]][ac] = pa[i];
    #pragma unroll
    for (int i = 0; i < 4; ++i) {
      Wt[wc + 0][wr[i]] = pw[i].x; Wt[wc + 1][wr[i]] = pw[i].y;
      Wt[wc + 2][wr[i]] = pw[i].z; Wt[wc + 3][wr[i]] = pw[i].w;
    }
    if (kt < 11) {
      int ko = (kt + 1) * 64;
      #pragma unroll
      for (int i = 0; i < 2; ++i)
        pa[i] = *(const float4*)&A[(size_t)(m0 + ar[i]) * HQ + ko + ac];
      #pragma unroll
      for (int i = 0; i < 4; ++i)
        pw[i] = *(const float4*)&W[(size_t)(n0 + wr[i]) * HQ + ko + wc];
    }
    __syncthreads();

    #pragma unroll
    for (int kk = 0; kk < 64; kk += 4) {
      float4 a[2], wv[4];
      #pragma unroll
      for (int j = 0; j < 2; ++j)
        a[j] = *(float4*)&As[2 * ty + j][kk];
      #pragma unroll
      for (int i = 0; i < 4; ++i)
        wv[i] = *(float4*)&Wt[kk + i][4 * tx];
      #pragma unroll
      for (int i = 0; i < 4; ++i) {
        #pragma unroll
        for (int j = 0; j < 2; ++j) {
          float av = ((const float*)&a[j])[i];
          acc[j][0] = fmaf(av, wv[i].x, acc[j][0]);
          acc[j][1] = fmaf(av, wv[i].y, acc[j][1]);
          acc[j][2] = fmaf(av, wv[i].z, acc[j][2]);
          acc[j][3] = fmaf(av, wv[i].w, acc[j][3]);
        }
      }
    }
  }

  const int l  = n0 / HQ;
  const int h0 = n0 % HQ;
  float4 bv = *(const float4*)&bs[n0 + 4 * tx];
  #pragma unroll
  for (int j = 0; j < 2; ++j) {
    int m  = m0 + 2 * ty + j;
    int bb = m / SQ, s = m % SQ;
    ushort4 v;
    v.x = bf16_rne(acc[j][0] + bv.x); v.y = bf16_rne(acc[j][1] + bv.y);
    v.z = bf16_rne(acc[j][2] + bv.z); v.w = bf16_rne(acc[j][3] + bv.w);
    *(ushort4*)(out + (((size_t)(bb * LQ + l) * SQ + s) * HQ) + h0 + 4 * tx) = v;
  }
}

__global__ __launch_bounds__(256) void pack_kernel(const float* __restrict__ cw,
                                                   float* __restrict__ clp) {
  int i = blockIdx.x * 256 + threadIdx.x;
  int l = i / HQ, h = i % HQ;
  clp[i] = cw[h * LQ + l];
}

// ---------------- Kernel 2: pairwise gelu-reduce (bf16 in, R5 structure) ---------------
// out[b,s,t,l] = sum_h gelu(hs[b,l,s,h] + ht[b,l,t,h]) * clp[l,h]
// 16s x 16t per block, chunk=128 (LDS 16.9KB), both tiles staged (bf16->f32 at stage).
__global__ __launch_bounds__(256, 4) void pair_kernel(
    const unsigned short* __restrict__ hsrc, const unsigned short* __restrict__ htgt,
    const float* __restrict__ clp, float* __restrict__ out)
{
  // XCD-chunked bijective swizzle (1152 = 8*144)
  int id  = blockIdx.x + 12 * (blockIdx.y + 12 * blockIdx.z);
  int nid = (id & 7) * 144 + (id >> 3);
  int bix = nid % 12, biy = (nid / 12) % 12, bl = nid / 144;

  const int bb = bl >> 2, l = bl & 3;
  const int s0 = bix * 16;
  const int t0 = biy * 16;
  const int tid = threadIdx.x;
  const int tt = tid & 15;
  const int ts = tid >> 4;

  __shared__ float hstile[16][132];   // pad 132 (=4 mod 32): conflict-free col reads
  __shared__ float httile[16][132];

  const unsigned short* hs_g = hsrc + ((size_t)bl * SQ + s0) * HQ;
  const unsigned short* ht_g = htgt + ((size_t)bl * SQ + t0) * HQ;
  const float* clp_l = clp + l * HQ;  // uniform across block -> s_load

  const int srow = tid >> 4;          // staging: row 0..15
  const int scol = (tid & 15) * 8;    // col chunk 0..120

  f2 acc = {0.f, 0.f};
  #pragma unroll 1
  for (int ck = 0; ck < 6; ++ck) {
    __syncthreads();
    {
      u16x8 uh = *(const u16x8*)&hs_g[(size_t)srow * HQ + ck * 128 + scol];
      u16x8 ut = *(const u16x8*)&ht_g[(size_t)srow * HQ + ck * 128 + scol];
      float4 f0, f1, g0, g1;
      f0.x = b2f(uh[0]); f0.y = b2f(uh[1]); f0.z = b2f(uh[2]); f0.w = b2f(uh[3]);
      f1.x = b2f(uh[4]); f1.y = b2f(uh[5]); f1.z = b2f(uh[6]); f1.w = b2f(uh[7]);
      g0.x = b2f(ut[0]); g0.y = b2f(ut[1]); g0.z = b2f(ut[2]); g0.w = b2f(ut[3]);
      g1.x = b2f(ut[4]); g1.y = b2f(ut[5]); g1.z = b2f(ut[6]); g1.w = b2f(ut[7]);
      *(float4*)&hstile[srow][scol]     = f0;
      *(float4*)&hstile[srow][scol + 4] = f1;
      *(float4*)&httile[srow][scol]     = g0;
      *(float4*)&httile[srow][scol + 4] = g1;
    }
    __syncthreads();

    #pragma unroll 4
    for (int k = 0; k < 128; k += 4) {
      float4 a  = *(float4*)&hstile[ts][k];         // 16-lane broadcast
      float4 b  = *(float4*)&httile[tt][k];         // conflict-free (pad 132)
      float4 c4 = *(const float4*)&clp_l[ck * 128 + k];
      const f2* ap = (const f2*)&a;
      const f2* bp = (const f2*)&b;
      const f2* cp = (const f2*)&c4;
      acc = __builtin_elementwise_fma(gelu2(ap[0] + bp[0]), cp[0], acc);
      acc = __builtin_elementwise_fma(gelu2(ap[1] + bp[1]), cp[1], acc);
    }
  }

  out[(((size_t)bb * SQ + (s0 + ts)) * SQ + (t0 + tt)) * LQ + l] = acc.x + acc.y;
}

extern "C" void kernel_launch(void* const* d_in, const int* in_sizes, int n_in,
                              void* d_out, int out_size, void* d_ws, size_t ws_size,
                              hipStream_t stream) {
  const float* pooled = (const float*)d_in[0];
  const float* Wsrc   = (const float*)d_in[1];
  const float* bsrc   = (const float*)d_in[2];
  const float* Wtgt   = (const float*)d_in[3];
  const float* btgt   = (const float*)d_in[4];
  const float* cw     = (const float*)d_in[5];
  float* out = (float*)d_out;

  const size_t nhs = (size_t)BQ * LQ * SQ * HQ;               // 1,179,648
  float* clp = (float*)d_ws;                                  // [L][H] f32 (12 KB)
  unsigned short* hsb = (unsigned short*)(clp + LQ * HQ);     // [B][L][S][H] bf16
  unsigned short* htb = hsb + nhs;
  unsigned short* Ab  = htb + nhs;                            // packed frags
  unsigned short* Wsb = Ab + (size_t)BQ * SQ * HQ;
  unsigned short* Wtb = Wsb + (size_t)LQ * HQ * HQ;

  size_t need_full = (size_t)(LQ * HQ) * 4 + 2 * nhs * 2 +
                     (size_t)(BQ * SQ * HQ + 2 * LQ * HQ * HQ) * 2;   // ~14.8 MB

  if (ws_size >= need_full) {
    prep_kernel<<<dim3(2460), 256, 0, stream>>>(pooled, Wsrc, Wtgt, cw, Ab, Wsb, Wtb, clp);
    proj_mfma<<<dim3(12, 96, 2), 64, 0, stream>>>(Ab, Wsb, Wtb, bsrc, btgt, hsb, htb);
  } else {                                                    // needs only ~4.8 MB
    pack_kernel<<<dim3(12), 256, 0, stream>>>(cw, clp);
    proj_kernel<<<dim3(12, 48, 2), 256, 0, stream>>>(pooled, Wsrc, bsrc, Wtgt, btgt, hsb, htb);
  }
  pair_kernel<<<dim3(12, 12, 8), 256, 0, stream>>>(hsb, htb, clp, out);
}